// Round 1
// baseline (2920.434 us; speedup 1.0000x reference)
//
#include <hip/hip_runtime.h>
#include <hip/hip_bf16.h>

// Problem dims (fixed by reference)
#define BB 4
#define TT 1024
#define EE 1024
#define HH 16
#define DD 64

// ---------------------------------------------------------------------------
// Generic fp32 tiled GEMM: C[M,1024] = A[M,1024] @ W[1024,1024], epilogue by mode.
// mode 0: q -> out0 = acc*scale + bias0[n], out1 = acc*scale + bias1[n], layout [B,H,T,D]
// mode 1: k/v -> out0 = acc, layout [B,H,T,D]
// mode 3: r -> out0 = acc, layout [H,P,D]  (m == p)
// mode 4: merge -> out0[m*1024+n] = acc + bias0[n]
// ---------------------------------------------------------------------------
__global__ void __launch_bounds__(256) gemm_proj_kernel(
    const float* __restrict__ A, const float* __restrict__ W,
    float* __restrict__ out0, float* __restrict__ out1,
    const float* __restrict__ bias0, const float* __restrict__ bias1,
    float scale, int mode)
{
    __shared__ float As[16][68];   // [kk][mm], padded for alignment/banks
    __shared__ float Bs[16][64];   // [kk][nn]

    const int tid = threadIdx.x;
    const int tx = tid & 15;       // n direction
    const int ty = tid >> 4;       // m direction
    const int m0 = blockIdx.y * 64;
    const int n0 = blockIdx.x * 64;

    float acc[4][4];
    #pragma unroll
    for (int i = 0; i < 4; i++)
        #pragma unroll
        for (int j = 0; j < 4; j++) acc[i][j] = 0.f;

    for (int k0 = 0; k0 < 1024; k0 += 16) {
        // A tile: 64 rows x 16 k, stored transposed As[kk][mm]
        {
            int e = tid * 4;
            int kk = e & 15;
            int mm = e >> 4;
            float4 a4 = *reinterpret_cast<const float4*>(A + (size_t)(m0 + mm) * 1024 + k0 + kk);
            As[kk + 0][mm] = a4.x;
            As[kk + 1][mm] = a4.y;
            As[kk + 2][mm] = a4.z;
            As[kk + 3][mm] = a4.w;
        }
        // B tile: 16 k x 64 n
        {
            int e = tid * 4;
            int nn = e & 63;
            int kk = e >> 6;
            float4 b4 = *reinterpret_cast<const float4*>(W + (size_t)(k0 + kk) * 1024 + n0 + nn);
            *reinterpret_cast<float4*>(&Bs[kk][nn]) = b4;
        }
        __syncthreads();

        #pragma unroll
        for (int kk = 0; kk < 16; kk++) {
            float a[4], b[4];
            *reinterpret_cast<float4*>(a) = *reinterpret_cast<const float4*>(&As[kk][ty * 4]);
            *reinterpret_cast<float4*>(b) = *reinterpret_cast<const float4*>(&Bs[kk][tx * 4]);
            #pragma unroll
            for (int i = 0; i < 4; i++)
                #pragma unroll
                for (int j = 0; j < 4; j++)
                    acc[i][j] += a[i] * b[j];
        }
        __syncthreads();
    }

    // epilogue
    #pragma unroll
    for (int i = 0; i < 4; i++) {
        int m = m0 + ty * 4 + i;
        #pragma unroll
        for (int j = 0; j < 4; j++) {
            int n = n0 + tx * 4 + j;
            float val = acc[i][j];
            if (mode == 0) {
                val *= scale;
                int h = n >> 6, d = n & 63;
                int b = m >> 10, t = m & 1023;
                size_t idx = (((size_t)(b * HH + h)) * TT + t) * DD + d;
                out0[idx] = val + bias0[n];
                out1[idx] = val + bias1[n];
            } else if (mode == 1) {
                int h = n >> 6, d = n & 63;
                int b = m >> 10, t = m & 1023;
                size_t idx = (((size_t)(b * HH + h)) * TT + t) * DD + d;
                out0[idx] = val;
            } else if (mode == 3) {
                int h = n >> 6, d = n & 63;
                size_t idx = ((size_t)h * TT + m) * DD + d;
                out0[idx] = val;
            } else {  // mode 4
                out0[(size_t)m * 1024 + n] = val + bias0[n];
            }
        }
    }
}

// ---------------------------------------------------------------------------
// Fused attention: one block per (b, h, 8-row q-block).
// Scores (content + exact rel_shift semantics) -> softmax -> PV.
// rel_shift(i,j):  j<=i   : qv[i]   . r[T-1+j-i]
//                  j==i+1 : 0
//                  j>=i+2 : qv[i+1] . r[j-i-2]
// ---------------------------------------------------------------------------
__global__ void __launch_bounds__(256) attn_kernel(
    const float* __restrict__ qu, const float* __restrict__ qv,
    const float* __restrict__ kb, const float* __restrict__ vb,
    const float* __restrict__ rb, float* __restrict__ att)
{
    const int T = TT, QB = 8;
    __shared__ float S[QB][1024];     // 32 KB scores
    __shared__ float Ks[64][66];      // 16.5 KB K/V chunk (bank-friendly pad)
    __shared__ float Qu[QB][64];
    __shared__ float Qv[QB + 1][64];

    const int tid = threadIdx.x;
    const int iblk = blockIdx.x;      // 0..127
    const int h = blockIdx.y;
    const int b = blockIdx.z;
    const int i0 = iblk * QB;
    const size_t base = ((size_t)(b * HH + h)) * T * DD;

    // load Qu (8 rows), Qv (9 rows; extra row only used for i=7, guarded)
    for (int e = tid; e < QB * 64; e += 256)
        Qu[e >> 6][e & 63] = qu[base + (size_t)(i0 + (e >> 6)) * 64 + (e & 63)];
    for (int e = tid; e < (QB + 1) * 64; e += 256) {
        int row = e >> 6, gi = i0 + row;
        Qv[row][e & 63] = (gi < T) ? qv[base + (size_t)gi * 64 + (e & 63)] : 0.f;
    }
    __syncthreads();

    const float* rh = rb + (size_t)h * T * DD;
    const int jl = tid & 63;
    const int ih = tid >> 6;   // 0..3

    // ---- scores ----
    for (int jc = 0; jc < T; jc += 64) {
        // stage K chunk
        {
            int e = tid * 4;
            #pragma unroll
            for (int rep = 0; rep < 4; rep++, e += 1024) {
                int row = e >> 6, col = e & 63;
                float4 k4 = *reinterpret_cast<const float4*>(kb + base + (size_t)(jc + row) * 64 + col);
                Ks[row][col] = k4.x; Ks[row][col + 1] = k4.y;
                Ks[row][col + 2] = k4.z; Ks[row][col + 3] = k4.w;
            }
        }
        __syncthreads();

        #pragma unroll
        for (int r2 = 0; r2 < 2; r2++) {
            const int i = ih + r2 * 4;
            const int ig = i0 + i;
            const int jg = jc + jl;
            // content: (q+u) . k
            float acc = 0.f;
            #pragma unroll
            for (int d = 0; d < 64; d += 2) {
                float2 k2 = *reinterpret_cast<const float2*>(&Ks[jl][d]);
                float2 q2 = *reinterpret_cast<const float2*>(&Qu[i][d]);
                acc += q2.x * k2.x + q2.y * k2.y;
            }
            // relative (exact rel_shift semantics)
            int p = -1, qrow = 0;
            if (jg <= ig)            { p = T - 1 + jg - ig; qrow = i; }
            else if (jg >= ig + 2)   { p = jg - ig - 2;     qrow = i + 1; }
            if (p >= 0) {
                const float4* rp = reinterpret_cast<const float4*>(rh + (size_t)p * 64);
                const float4* qp = reinterpret_cast<const float4*>(&Qv[qrow][0]);
                #pragma unroll
                for (int dd = 0; dd < 16; dd++) {
                    float4 r4 = rp[dd];
                    float4 q4 = qp[dd];
                    acc += q4.x * r4.x + q4.y * r4.y + q4.z * r4.z + q4.w * r4.w;
                }
            }
            S[i][jg] = acc;
        }
        __syncthreads();
    }

    // ---- softmax (full row, no mask) ----
    const int row = tid >> 5;   // 0..7
    const int l = tid & 31;
    {
        float m = -1e30f;
        for (int j = l; j < T; j += 32) m = fmaxf(m, S[row][j]);
        #pragma unroll
        for (int off = 16; off; off >>= 1) m = fmaxf(m, __shfl_xor(m, off, 32));
        float s = 0.f;
        for (int j = l; j < T; j += 32) {
            float e = __expf(S[row][j] - m);
            S[row][j] = e;
            s += e;
        }
        #pragma unroll
        for (int off = 16; off; off >>= 1) s += __shfl_xor(s, off, 32);
        const float inv = 1.f / s;
        for (int j = l; j < T; j += 32) S[row][j] *= inv;
    }
    __syncthreads();

    // ---- PV ----
    const int d2 = (tid & 31) * 2;
    float accx = 0.f, accy = 0.f;
    for (int jc = 0; jc < T; jc += 64) {
        {
            int e = tid * 4;
            #pragma unroll
            for (int rep = 0; rep < 4; rep++, e += 1024) {
                int rr = e >> 6, cc = e & 63;
                float4 v4 = *reinterpret_cast<const float4*>(vb + base + (size_t)(jc + rr) * 64 + cc);
                Ks[rr][cc] = v4.x; Ks[rr][cc + 1] = v4.y;
                Ks[rr][cc + 2] = v4.z; Ks[rr][cc + 3] = v4.w;
            }
        }
        __syncthreads();
        #pragma unroll
        for (int j = 0; j < 64; j++) {
            float w = S[row][jc + j];
            float2 vv = *reinterpret_cast<const float2*>(&Ks[j][d2]);
            accx += w * vv.x;
            accy += w * vv.y;
        }
        __syncthreads();
    }
    // att layout [B,T,H,D] == [BT, E] for merge GEMM
    size_t oi = (((size_t)b * T + (i0 + row)) * HH + h) * DD + d2;
    att[oi] = accx;
    att[oi + 1] = accy;
}

extern "C" void kernel_launch(void* const* d_in, const int* in_sizes, int n_in,
                              void* d_out, int out_size, void* d_ws, size_t ws_size,
                              hipStream_t stream) {
    const float* x    = (const float*)d_in[0];
    const float* pos  = (const float*)d_in[1];
    const float* Wq   = (const float*)d_in[2];
    const float* Wk   = (const float*)d_in[3];
    const float* Wv   = (const float*)d_in[4];
    const float* Wr   = (const float*)d_in[5];
    const float* ub   = (const float*)d_in[6];   // r_w_bias [H*D]
    const float* vb   = (const float*)d_in[7];   // r_r_bias [H*D]
    const float* mW   = (const float*)d_in[8];
    const float* mb   = (const float*)d_in[9];
    float* out = (float*)d_out;
    float* ws  = (float*)d_ws;

    const size_t M1 = 1u << 20;  // 1M floats
    float* qu_ws  = ws;            // 4M  [B,H,T,D]
    float* qv_ws  = ws + 4 * M1;   // 4M
    float* k_ws   = ws + 8 * M1;   // 4M
    float* v_ws   = ws + 12 * M1;  // 4M
    float* r_ws   = ws + 16 * M1;  // 1M  [H,T,D]
    float* att_ws = ws + 17 * M1;  // 4M  [B,T,H,D]

    const float scale = 0.125f;  // D^-0.5

    dim3 blk(256);
    dim3 grid_q(16, 64);   // N/64, (B*T)/64
    dim3 grid_r(16, 16);   // N/64, T/64

    // projections
    hipLaunchKernelGGL(gemm_proj_kernel, grid_q, blk, 0, stream,
                       x, Wq, qu_ws, qv_ws, ub, vb, scale, 0);
    hipLaunchKernelGGL(gemm_proj_kernel, grid_q, blk, 0, stream,
                       x, Wk, k_ws, nullptr, nullptr, nullptr, 1.f, 1);
    hipLaunchKernelGGL(gemm_proj_kernel, grid_q, blk, 0, stream,
                       x, Wv, v_ws, nullptr, nullptr, nullptr, 1.f, 1);
    hipLaunchKernelGGL(gemm_proj_kernel, grid_r, blk, 0, stream,
                       pos, Wr, r_ws, nullptr, nullptr, nullptr, 1.f, 3);

    // fused attention
    dim3 grid_a(TT / 8, HH, BB);
    hipLaunchKernelGGL(attn_kernel, grid_a, blk, 0, stream,
                       qu_ws, qv_ws, k_ws, v_ws, r_ws, att_ws);

    // merge
    hipLaunchKernelGGL(gemm_proj_kernel, grid_q, blk, 0, stream,
                       att_ws, mW, out, nullptr, mb, nullptr, 1.f, 4);
}

// Round 2
// 777.874 us; speedup vs baseline: 3.7544x; 3.7544x over previous
//
#include <hip/hip_runtime.h>
#include <hip/hip_bf16.h>

#define BB 4
#define TT 1024
#define EE 1024
#define HH 16
#define DD 64

typedef unsigned short ushort_t;
typedef unsigned int uint_t;
typedef __attribute__((ext_vector_type(8))) short short8;
typedef __attribute__((ext_vector_type(4))) float f32x4;

__device__ __forceinline__ ushort_t f2bf(float f) {
  uint_t u = __float_as_uint(f);
  u += 0x7fffu + ((u >> 16) & 1u);
  return (ushort_t)(u >> 16);
}
__device__ __forceinline__ float bf2f(ushort_t s) {
  return __uint_as_float(((uint_t)s) << 16);
}

// async global->LDS, 16B per lane; dst is wave-uniform base (HW adds lane*16)
__device__ __forceinline__ void gload16(const ushort_t* src, ushort_t* dst) {
  __builtin_amdgcn_global_load_lds(
      (const __attribute__((address_space(1))) void*)src,
      (__attribute__((address_space(3))) void*)dst, 16, 0, 0);
}

// Stage 8 rows (1KB) of a [rows][64 bf16] LDS tile (rows are 128B), with the
// XOR bank-swizzle pre-applied on the GLOBAL source address (LDS stays linear).
// swizzled read: byte_in_row' = byte_in_row ^ ((row&7)<<4)
__device__ __forceinline__ void stage8(ushort_t* region, const ushort_t* grow0,
                                       int r0, int lane, int rmax) {
  int flat16 = r0 * 8 + lane;
  int row = flat16 >> 3;
  int ch = flat16 & 7;
  int gr = row > rmax ? rmax : row;
  const ushort_t* src = grow0 + (size_t)gr * 64 + ((((ch << 4) ^ ((row & 7) << 4))) >> 1);
  gload16(src, region + r0 * 64);
}

// swizzled LDS read of an 8-bf16 fragment from a [rows][64] tile
__device__ __forceinline__ short8 ldsw(const ushort_t* base, int row, int offB) {
  const char* p = (const char*)base + row * 128 + (offB ^ ((row & 7) << 4));
  return *(const short8*)p;
}

// ---------------------------------------------------------------------------
// fp32 tiled GEMM with mode-dependent epilogue (bf16 outputs for attn inputs)
// mode 0: qu=bf16(acc*scale+u), qv=bf16(acc*scale+v), layout [B,H,T,D]
// mode 1: bf16(acc), layout [B,H,T,D]
// mode 3: bf16(acc), layout [H,P,D]
// mode 4: f32 acc + bias, row-major [M,1024]
// ---------------------------------------------------------------------------
__global__ void __launch_bounds__(256) gemm_proj_kernel(
    const float* __restrict__ A, const float* __restrict__ W,
    void* __restrict__ out0, void* __restrict__ out1,
    const float* __restrict__ bias0, const float* __restrict__ bias1,
    float scale, int mode)
{
    __shared__ float As[16][68];
    __shared__ float Bs[16][64];

    const int tid = threadIdx.x;
    const int tx = tid & 15;
    const int ty = tid >> 4;
    const int m0 = blockIdx.y * 64;
    const int n0 = blockIdx.x * 64;

    float acc[4][4];
    #pragma unroll
    for (int i = 0; i < 4; i++)
        #pragma unroll
        for (int j = 0; j < 4; j++) acc[i][j] = 0.f;

    for (int k0 = 0; k0 < 1024; k0 += 16) {
        {
            int e = tid * 4;
            int kk = e & 15;
            int mm = e >> 4;
            float4 a4 = *reinterpret_cast<const float4*>(A + (size_t)(m0 + mm) * 1024 + k0 + kk);
            As[kk + 0][mm] = a4.x;
            As[kk + 1][mm] = a4.y;
            As[kk + 2][mm] = a4.z;
            As[kk + 3][mm] = a4.w;
        }
        {
            int e = tid * 4;
            int nn = e & 63;
            int kk = e >> 6;
            float4 b4 = *reinterpret_cast<const float4*>(W + (size_t)(k0 + kk) * 1024 + n0 + nn);
            *reinterpret_cast<float4*>(&Bs[kk][nn]) = b4;
        }
        __syncthreads();

        #pragma unroll
        for (int kk = 0; kk < 16; kk++) {
            float a[4], b[4];
            *reinterpret_cast<float4*>(a) = *reinterpret_cast<const float4*>(&As[kk][ty * 4]);
            *reinterpret_cast<float4*>(b) = *reinterpret_cast<const float4*>(&Bs[kk][tx * 4]);
            #pragma unroll
            for (int i = 0; i < 4; i++)
                #pragma unroll
                for (int j = 0; j < 4; j++)
                    acc[i][j] += a[i] * b[j];
        }
        __syncthreads();
    }

    #pragma unroll
    for (int i = 0; i < 4; i++) {
        int m = m0 + ty * 4 + i;
        #pragma unroll
        for (int j = 0; j < 4; j++) {
            int n = n0 + tx * 4 + j;
            float val = acc[i][j];
            if (mode == 0) {
                val *= scale;
                int h = n >> 6, d = n & 63;
                int b = m >> 10, t = m & 1023;
                size_t idx = (((size_t)(b * HH + h)) * TT + t) * DD + d;
                ((ushort_t*)out0)[idx] = f2bf(val + bias0[n]);
                ((ushort_t*)out1)[idx] = f2bf(val + bias1[n]);
            } else if (mode == 1) {
                int h = n >> 6, d = n & 63;
                int b = m >> 10, t = m & 1023;
                size_t idx = (((size_t)(b * HH + h)) * TT + t) * DD + d;
                ((ushort_t*)out0)[idx] = f2bf(val);
            } else if (mode == 3) {
                int h = n >> 6, d = n & 63;
                size_t idx = ((size_t)h * TT + m) * DD + d;
                ((ushort_t*)out0)[idx] = f2bf(val);
            } else {
                ((float*)out0)[(size_t)m * 1024 + n] = val + bias0[n];
            }
        }
    }
}

// ---------------------------------------------------------------------------
// MFMA flash attention with exact Transformer-XL rel_shift via windowed G GEMM.
// Block = (b, h, 64 q-rows), 4 waves; each wave owns 16 q-rows.
// rel_shift(i,j): j<=i -> qv[i].r[T-1+j-i]; j==i+1 -> 0; j>=i+2 -> qv[i+1].r[j-i-2]
// ---------------------------------------------------------------------------
__global__ void __launch_bounds__(256, 3) attn_mfma_kernel(
    const ushort_t* __restrict__ qu_g, const ushort_t* __restrict__ qv_g,
    const ushort_t* __restrict__ k_g, const ushort_t* __restrict__ v_g,
    const ushort_t* __restrict__ r_g, float* __restrict__ att)
{
    __shared__ ushort_t sQu[64 * 64];   // swizzled 128B rows
    __shared__ ushort_t sQv[72 * 64];   // swizzled, rows i0..i0+64 (+pad)
    __shared__ ushort_t sK[64 * 64];    // swizzled
    __shared__ ushort_t sVt[64 * 72];   // V^T tile: [d][j], 144B rows (pad)
    __shared__ ushort_t sG[4 * 2176];   // per-wave: G col-major [128][16] / P [16][72]

    const int tid = threadIdx.x;
    const int w = tid >> 6;
    const int lane = tid & 63;
    const int g = lane >> 4;
    const int cl = lane & 15;

    const int i0 = blockIdx.x * 64;
    const int h = blockIdx.y;
    const int b = blockIdx.z;
    const size_t base_bh = ((size_t)(b * HH + h)) * TT * DD;
    const ushort_t* rh = r_g + (size_t)h * TT * DD;

    ushort_t* Gw = sG + w * 2176;       // 4352 B per wave
    ushort_t* Pb = Gw;                  // P aliases G (used after gathers)

    // ---- prologue: stage Qu (64 rows) and Qv (rows i0..i0+64) ----
    {
        const ushort_t* qub = qu_g + base_bh + (size_t)i0 * 64;
        stage8(sQu, qub, 16 * w, lane, 63);
        stage8(sQu, qub, 16 * w + 8, lane, 63);
        const ushort_t* qvb = qv_g + base_bh + (size_t)i0 * 64;
        int qvmax = 1023 - i0;          // clamp local row (garbage rows never gathered)
        stage8(sQv, qvb, 16 * w, lane, qvmax);
        stage8(sQv, qvb, 16 * w + 8, lane, qvmax);
        if (w == 0) stage8(sQv, qvb, 64, lane, qvmax);
    }
    __syncthreads();

    // A-fragments of Qu for this wave (row = 16w + (lane&15))
    short8 aQ0 = ldsw(sQu, 16 * w + cl, 16 * g);
    short8 aQ1 = ldsw(sQu, 16 * w + cl, 64 + 16 * g);

    f32x4 Oa[4];
    #pragma unroll
    for (int q = 0; q < 4; q++) Oa[q] = (f32x4){0.f, 0.f, 0.f, 0.f};
    float mrun[4] = {-1e30f, -1e30f, -1e30f, -1e30f};
    float lrun[4] = {0.f, 0.f, 0.f, 0.f};

    for (int jt16 = 0; jt16 < 16; jt16++) {
        const int j0 = jt16 * 64;
        const int dji = j0 - i0;

        // ---- stage K (async, swizzled) and V^T (reg transpose) ----
        {
            const ushort_t* kb = k_g + base_bh + (size_t)j0 * 64;
            stage8(sK, kb, 16 * w, lane, 63);
            stage8(sK, kb, 16 * w + 8, lane, 63);
        }
        {
            int jj = tid & 63;
            int d0 = (tid >> 6) * 16;
            const ushort_t* vs = v_g + base_bh + (size_t)(j0 + jj) * 64 + d0;
            short8 v0 = *(const short8*)vs;
            short8 v1 = *(const short8*)(vs + 8);
            #pragma unroll
            for (int e = 0; e < 8; e++) sVt[(d0 + e) * 72 + jj] = (ushort_t)v0[e];
            #pragma unroll
            for (int e = 0; e < 8; e++) sVt[(d0 + 8 + e) * 72 + jj] = (ushort_t)v1[e];
        }
        __syncthreads();

        // ---- content scores: S = Qu @ K^T ----
        f32x4 sacc[4];
        #pragma unroll
        for (int jt = 0; jt < 4; jt++) sacc[jt] = (f32x4){0.f, 0.f, 0.f, 0.f};
        #pragma unroll
        for (int jt = 0; jt < 4; jt++) {
            int krow = jt * 16 + cl;
            short8 b0 = ldsw(sK, krow, 16 * g);
            short8 b1 = ldsw(sK, krow, 64 + 16 * g);
            sacc[jt] = __builtin_amdgcn_mfma_f32_16x16x32_bf16(aQ0, b0, sacc[jt], 0, 0, 0);
            sacc[jt] = __builtin_amdgcn_mfma_f32_16x16x32_bf16(aQ1, b1, sacc[jt], 0, 0, 0);
        }

        // ---- relative scores via windowed G GEMM + gather ----
        // branch1: j<=i : G1[r][m] = qv[i0+16w+r] . r[cbase1+m], add where m1<=lim
        if (dji <= 0) {
            int cbase = 960 + dji;               // T-64 + j0-i0
            int nsub = (dji == 0) ? 4 : 8;
            int arow = 16 * w + cl;
            short8 aV0 = ldsw(sQv, arow, 16 * g);
            short8 aV1 = ldsw(sQv, arow, 64 + 16 * g);
            for (int sub = 0; sub < nsub; sub++) {
                int m = sub * 16 + cl;
                int rr = cbase + m;
                rr = rr < 0 ? 0 : (rr > 1023 ? 1023 : rr);
                const ushort_t* rp = rh + (size_t)rr * 64 + 8 * g;
                f32x4 gacc = (f32x4){0.f, 0.f, 0.f, 0.f};
                gacc = __builtin_amdgcn_mfma_f32_16x16x32_bf16(aV0, *(const short8*)rp, gacc, 0, 0, 0);
                gacc = __builtin_amdgcn_mfma_f32_16x16x32_bf16(aV1, *(const short8*)(rp + 32), gacc, 0, 0, 0);
                uint2 pk;
                pk.x = (uint_t)f2bf(gacc[0]) | ((uint_t)f2bf(gacc[1]) << 16);
                pk.y = (uint_t)f2bf(gacc[2]) | ((uint_t)f2bf(gacc[3]) << 16);
                *(uint2*)(Gw + m * 16 + 4 * g) = pk;
            }
            int lim = 63 - dji;
            #pragma unroll
            for (int jt = 0; jt < 4; jt++)
                #pragma unroll
                for (int reg = 0; reg < 4; reg++) {
                    int m1 = 63 + jt * 16 + cl - 16 * w - 4 * g - reg;
                    if (m1 <= lim) sacc[jt][reg] += bf2f(Gw[m1 * 16 + 4 * g + reg]);
                }
        }
        // branch2: j>=i+2 : G2[r][m] = qv[i0+1+16w+r] . r[cb2+m]
        if (dji >= 0) {
            int cb2 = dji - 65; if (cb2 < 0) cb2 = 0;
            int nsub = (dji == 0) ? 4 : 8;
            int arow = 1 + 16 * w + cl;
            short8 aV0 = ldsw(sQv, arow, 16 * g);
            short8 aV1 = ldsw(sQv, arow, 64 + 16 * g);
            for (int sub = 0; sub < nsub; sub++) {
                int m = sub * 16 + cl;
                int rr = cb2 + m;
                rr = rr > 1023 ? 1023 : rr;
                const ushort_t* rp = rh + (size_t)rr * 64 + 8 * g;
                f32x4 gacc = (f32x4){0.f, 0.f, 0.f, 0.f};
                gacc = __builtin_amdgcn_mfma_f32_16x16x32_bf16(aV0, *(const short8*)rp, gacc, 0, 0, 0);
                gacc = __builtin_amdgcn_mfma_f32_16x16x32_bf16(aV1, *(const short8*)(rp + 32), gacc, 0, 0, 0);
                uint2 pk;
                pk.x = (uint_t)f2bf(gacc[0]) | ((uint_t)f2bf(gacc[1]) << 16);
                pk.y = (uint_t)f2bf(gacc[2]) | ((uint_t)f2bf(gacc[3]) << 16);
                *(uint2*)(Gw + m * 16 + 4 * g) = pk;
            }
            #pragma unroll
            for (int jt = 0; jt < 4; jt++)
                #pragma unroll
                for (int reg = 0; reg < 4; reg++) {
                    int dlt = dji + jt * 16 + cl - 16 * w - 4 * g - reg;
                    if (dlt >= 2) sacc[jt][reg] += bf2f(Gw[(dlt - 2 - cb2) * 16 + 4 * g + reg]);
                }
        }

        // ---- online softmax (rows = 4g+reg, row lives in 16 lanes) ----
        #pragma unroll
        for (int reg = 0; reg < 4; reg++) {
            float tmax = fmaxf(fmaxf(sacc[0][reg], sacc[1][reg]),
                               fmaxf(sacc[2][reg], sacc[3][reg]));
            #pragma unroll
            for (int msk = 1; msk <= 8; msk <<= 1) tmax = fmaxf(tmax, __shfl_xor(tmax, msk));
            float mnew = fmaxf(mrun[reg], tmax);
            float sc = __expf(mrun[reg] - mnew);
            mrun[reg] = mnew;
            float psum = 0.f;
            #pragma unroll
            for (int jt = 0; jt < 4; jt++) {
                float p = __expf(sacc[jt][reg] - mnew);
                psum += p;
                Pb[(4 * g + reg) * 72 + jt * 16 + cl] = f2bf(p);
            }
            #pragma unroll
            for (int msk = 1; msk <= 8; msk <<= 1) psum += __shfl_xor(psum, msk);
            lrun[reg] = lrun[reg] * sc + psum;
            #pragma unroll
            for (int q = 0; q < 4; q++) Oa[q][reg] *= sc;
        }

        // ---- PV: O += P @ V ----
        #pragma unroll
        for (int kk = 0; kk < 2; kk++) {
            short8 aP = *(const short8*)((const char*)Pb + cl * 144 + 64 * kk + 16 * g);
            #pragma unroll
            for (int q = 0; q < 4; q++) {
                int vrow = q * 16 + cl;
                short8 bV = *(const short8*)((const char*)sVt + vrow * 144 + 64 * kk + 16 * g);
                Oa[q] = __builtin_amdgcn_mfma_f32_16x16x32_bf16(aP, bV, Oa[q], 0, 0, 0);
            }
        }
        __syncthreads();
    }

    // ---- epilogue: normalize and store att [B,T,H,D] fp32 ----
    float inv[4];
    #pragma unroll
    for (int reg = 0; reg < 4; reg++) inv[reg] = 1.f / lrun[reg];
    #pragma unroll
    for (int q = 0; q < 4; q++)
        #pragma unroll
        for (int reg = 0; reg < 4; reg++) {
            int i = i0 + 16 * w + 4 * g + reg;
            int d = q * 16 + cl;
            att[(((size_t)(b * TT + i)) * HH + h) * DD + d] = Oa[q][reg] * inv[reg];
        }
}

extern "C" void kernel_launch(void* const* d_in, const int* in_sizes, int n_in,
                              void* d_out, int out_size, void* d_ws, size_t ws_size,
                              hipStream_t stream) {
    const float* x    = (const float*)d_in[0];
    const float* pos  = (const float*)d_in[1];
    const float* Wq   = (const float*)d_in[2];
    const float* Wk   = (const float*)d_in[3];
    const float* Wv   = (const float*)d_in[4];
    const float* Wr   = (const float*)d_in[5];
    const float* ub   = (const float*)d_in[6];
    const float* vb   = (const float*)d_in[7];
    const float* mW   = (const float*)d_in[8];
    const float* mb   = (const float*)d_in[9];
    float* out = (float*)d_out;

    char* wsb = (char*)d_ws;
    ushort_t* qu_g = (ushort_t*)(wsb);                       // 8 MB
    ushort_t* qv_g = (ushort_t*)(wsb + ((size_t)8 << 20));   // 8 MB
    ushort_t* k_g  = (ushort_t*)(wsb + ((size_t)16 << 20));  // 8 MB
    ushort_t* v_g  = (ushort_t*)(wsb + ((size_t)24 << 20));  // 8 MB
    ushort_t* r_g  = (ushort_t*)(wsb + ((size_t)32 << 20));  // 2 MB
    float*    att  = (float*)(wsb + ((size_t)34 << 20));     // 16 MB

    const float scale = 0.125f;

    dim3 blk(256);
    dim3 grid_q(16, 64);
    dim3 grid_r(16, 16);

    hipLaunchKernelGGL(gemm_proj_kernel, grid_q, blk, 0, stream,
                       x, Wq, (void*)qu_g, (void*)qv_g, ub, vb, scale, 0);
    hipLaunchKernelGGL(gemm_proj_kernel, grid_q, blk, 0, stream,
                       x, Wk, (void*)k_g, nullptr, nullptr, nullptr, 1.f, 1);
    hipLaunchKernelGGL(gemm_proj_kernel, grid_q, blk, 0, stream,
                       x, Wv, (void*)v_g, nullptr, nullptr, nullptr, 1.f, 1);
    hipLaunchKernelGGL(gemm_proj_kernel, grid_r, blk, 0, stream,
                       pos, Wr, (void*)r_g, nullptr, nullptr, nullptr, 1.f, 3);

    dim3 grid_a(TT / 64, HH, BB);
    hipLaunchKernelGGL(attn_mfma_kernel, grid_a, blk, 0, stream,
                       qu_g, qv_g, k_g, v_g, r_g, att);

    hipLaunchKernelGGL(gemm_proj_kernel, grid_q, blk, 0, stream,
                       att, mW, (void*)out, nullptr, mb, nullptr, 1.f, 4);
}

// Round 3
// 381.911 us; speedup vs baseline: 7.6469x; 2.0368x over previous
//
#include <hip/hip_runtime.h>
#include <hip/hip_bf16.h>

#define BB 4
#define TT 1024
#define EE 1024
#define HH 16
#define DD 64

typedef unsigned short ushort_t;
typedef unsigned int uint_t;
typedef __attribute__((ext_vector_type(8))) short short8;
typedef __attribute__((ext_vector_type(4))) float f32x4;

__device__ __forceinline__ ushort_t f2bf(float f) {
  uint_t u = __float_as_uint(f);
  u += 0x7fffu + ((u >> 16) & 1u);
  return (ushort_t)(u >> 16);
}
__device__ __forceinline__ float bf2f(ushort_t s) {
  return __uint_as_float(((uint_t)s) << 16);
}

// async global->LDS, 16B per lane; dst is wave-uniform base (HW adds lane*16)
__device__ __forceinline__ void gload16(const ushort_t* src, ushort_t* dst) {
  __builtin_amdgcn_global_load_lds(
      (const __attribute__((address_space(1))) void*)src,
      (__attribute__((address_space(3))) void*)dst, 16, 0, 0);
}

// ---------------------------------------------------------------------------
// flat fp32 -> bf16 convert (n multiple of 2048)
// ---------------------------------------------------------------------------
__global__ void __launch_bounds__(256) conv_flat(
    const float* __restrict__ in, ushort_t* __restrict__ out, int n) {
  int i = (blockIdx.x * 256 + threadIdx.x) * 8;
  if (i >= n) return;
  float4 a = *(const float4*)(in + i);
  float4 b = *(const float4*)(in + i + 4);
  uint4 o;
  o.x = (uint_t)f2bf(a.x) | ((uint_t)f2bf(a.y) << 16);
  o.y = (uint_t)f2bf(a.z) | ((uint_t)f2bf(a.w) << 16);
  o.z = (uint_t)f2bf(b.x) | ((uint_t)f2bf(b.y) << 16);
  o.w = (uint_t)f2bf(b.z) | ((uint_t)f2bf(b.w) << 16);
  *(uint4*)(out + i) = o;
}

// ---------------------------------------------------------------------------
// transpose + convert: Oh[n][k] = bf16(W[k][n]); optional lo residual
// grid (16,16), block 256, 64x64 tile
// ---------------------------------------------------------------------------
__global__ void __launch_bounds__(256) trans_conv(
    const float* __restrict__ W, ushort_t* __restrict__ Oh,
    ushort_t* __restrict__ Ol, int has_lo) {
  __shared__ float Ts[64][65];
  const int n0 = blockIdx.x * 64, k0 = blockIdx.y * 64;
  const int t = threadIdx.x;
  const int r = t >> 2, cs = (t & 3) * 16;
  const float* src = W + (size_t)(k0 + r) * 1024 + n0 + cs;
  #pragma unroll
  for (int e = 0; e < 16; e += 4) {
    float4 v4 = *(const float4*)(src + e);
    Ts[r][cs + e] = v4.x; Ts[r][cs + e + 1] = v4.y;
    Ts[r][cs + e + 2] = v4.z; Ts[r][cs + e + 3] = v4.w;
  }
  __syncthreads();
  ushort_t hb[16], lb[16];
  #pragma unroll
  for (int e = 0; e < 16; e++) {
    float v = Ts[cs + e][r];
    hb[e] = f2bf(v);
    lb[e] = f2bf(v - bf2f(hb[e]));
  }
  ushort_t* dh = Oh + (size_t)(n0 + r) * 1024 + k0 + cs;
  *(uint4*)dh = *(const uint4*)hb;
  *(uint4*)(dh + 8) = *(const uint4*)(hb + 8);
  if (has_lo) {
    ushort_t* dl = Ol + (size_t)(n0 + r) * 1024 + k0 + cs;
    *(uint4*)dl = *(const uint4*)lb;
    *(uint4*)(dl + 8) = *(const uint4*)(lb + 8);
  }
}

// ---------------------------------------------------------------------------
// MFMA GEMM (m97 structure): C[m][n] = A[m][:] . Bt[n][:]
// A [M][1024] bf16 row-major, Bt [1024][1024] bf16 (pre-transposed).
// 128x128 tile, BK=32, 4 waves, double-buffered LDS, global_load_lds x16.
// mode 0: fused qkv (widx = bx>>3: 0 -> qu/qv dual + scale + bias, 1 -> k, 2 -> v)
// mode 1: r -> [H,P,D]
// ---------------------------------------------------------------------------
__global__ void __launch_bounds__(256) mfma_gemm_proj(
    const ushort_t* __restrict__ A,
    const ushort_t* __restrict__ B0, const ushort_t* __restrict__ B1,
    const ushort_t* __restrict__ B2,
    ushort_t* __restrict__ o_qu, ushort_t* __restrict__ o_qv,
    ushort_t* __restrict__ o_k, ushort_t* __restrict__ o_v,
    const float* __restrict__ bias_u, const float* __restrict__ bias_v,
    int mode) {
  __shared__ ushort_t sA[2][128 * 32];
  __shared__ ushort_t sB[2][128 * 32];
  const int tid = threadIdx.x;
  const int w = tid >> 6, lane = tid & 63, g = lane >> 4, cl = lane & 15;
  const int wr = w >> 1, wc = w & 1;

  int widx, n0l;
  const ushort_t* Bt;
  if (mode == 0) {
    widx = blockIdx.x >> 3;
    n0l = (blockIdx.x & 7) * 128;
    Bt = (widx == 0) ? B0 : ((widx == 1) ? B1 : B2);
  } else {
    widx = 3;
    n0l = blockIdx.x * 128;
    Bt = B0;
  }
  const int m0 = blockIdx.y * 128;

  f32x4 acc[4][4];
  #pragma unroll
  for (int fi = 0; fi < 4; fi++)
    #pragma unroll
    for (int fj = 0; fj < 4; fj++) acc[fi][fj] = (f32x4){0.f, 0.f, 0.f, 0.f};

  auto STAGE = [&](int buf, int t) {
    const int k0b = t * 64;  // BK=32 elems = 64 bytes
    #pragma unroll
    for (int i = 0; i < 2; i++) {
      int cb = w * 128 + i * 64;
      int c = cb + lane;
      const char* sa = (const char*)A + (size_t)(m0 + (c >> 2)) * 2048 + k0b + (c & 3) * 16;
      gload16((const ushort_t*)sa, &sA[buf][cb * 8]);
      const char* sb = (const char*)Bt + (size_t)(n0l + (c >> 2)) * 2048 + k0b + (c & 3) * 16;
      gload16((const ushort_t*)sb, &sB[buf][cb * 8]);
    }
  };

  STAGE(0, 0);
  __syncthreads();
  int cur = 0;
  for (int t = 0; t < 32; t++) {
    if (t + 1 < 32) STAGE(cur ^ 1, t + 1);
    short8 af[4], bfr[4];
    #pragma unroll
    for (int f = 0; f < 4; f++) {
      af[f] = *(const short8*)&sA[cur][(wr * 64 + f * 16 + cl) * 32 + g * 8];
      bfr[f] = *(const short8*)&sB[cur][(wc * 64 + f * 16 + cl) * 32 + g * 8];
    }
    #pragma unroll
    for (int fi = 0; fi < 4; fi++)
      #pragma unroll
      for (int fj = 0; fj < 4; fj++)
        acc[fi][fj] = __builtin_amdgcn_mfma_f32_16x16x32_bf16(af[fi], bfr[fj], acc[fi][fj], 0, 0, 0);
    __syncthreads();
    cur ^= 1;
  }

  #pragma unroll
  for (int fi = 0; fi < 4; fi++)
    #pragma unroll
    for (int fj = 0; fj < 4; fj++)
      #pragma unroll
      for (int reg = 0; reg < 4; reg++) {
        int m = m0 + wr * 64 + fi * 16 + 4 * g + reg;
        int n = n0l + wc * 64 + fj * 16 + cl;
        float val = acc[fi][fj][reg];
        int h = n >> 6, d = n & 63;
        if (mode == 0) {
          int b = m >> 10, tt = m & 1023;
          size_t idx = (((size_t)(b * HH + h)) * TT + tt) * DD + d;
          if (widx == 0) {
            float s = val * 0.125f;
            o_qu[idx] = f2bf(s + bias_u[n]);
            o_qv[idx] = f2bf(s + bias_v[n]);
          } else if (widx == 1) {
            o_k[idx] = f2bf(val);
          } else {
            o_v[idx] = f2bf(val);
          }
        } else {
          size_t idx = ((size_t)h * TT + m) * DD + d;
          o_qu[idx] = f2bf(val);
        }
      }
}

// ---------------------------------------------------------------------------
// Split-bf16 merge GEMM: out = (Ah+Al) @ (Wh+Wl)^T + b  (drop Al@Wl term)
// Ah/Al [4096][1024] bf16, Bh/Bl [1024][1024] bf16 transposed. fp32 out.
// ---------------------------------------------------------------------------
__global__ void __launch_bounds__(256) mfma_gemm_merge(
    const ushort_t* __restrict__ Ah, const ushort_t* __restrict__ Al,
    const ushort_t* __restrict__ Bh, const ushort_t* __restrict__ Bl,
    const float* __restrict__ bias, float* __restrict__ out) {
  __shared__ ushort_t sAh[2][128 * 32], sAl[2][128 * 32];
  __shared__ ushort_t sBh[2][128 * 32], sBl[2][128 * 32];
  const int tid = threadIdx.x;
  const int w = tid >> 6, lane = tid & 63, g = lane >> 4, cl = lane & 15;
  const int wr = w >> 1, wc = w & 1;
  const int n0l = blockIdx.x * 128;
  const int m0 = blockIdx.y * 128;

  f32x4 acc[4][4];
  #pragma unroll
  for (int fi = 0; fi < 4; fi++)
    #pragma unroll
    for (int fj = 0; fj < 4; fj++) acc[fi][fj] = (f32x4){0.f, 0.f, 0.f, 0.f};

  auto STAGE = [&](int buf, int t) {
    const int k0b = t * 64;
    #pragma unroll
    for (int i = 0; i < 2; i++) {
      int cb = w * 128 + i * 64;
      int c = cb + lane;
      size_t offA = (size_t)(m0 + (c >> 2)) * 2048 + k0b + (c & 3) * 16;
      size_t offB = (size_t)(n0l + (c >> 2)) * 2048 + k0b + (c & 3) * 16;
      gload16((const ushort_t*)((const char*)Ah + offA), &sAh[buf][cb * 8]);
      gload16((const ushort_t*)((const char*)Al + offA), &sAl[buf][cb * 8]);
      gload16((const ushort_t*)((const char*)Bh + offB), &sBh[buf][cb * 8]);
      gload16((const ushort_t*)((const char*)Bl + offB), &sBl[buf][cb * 8]);
    }
  };

  STAGE(0, 0);
  __syncthreads();
  int cur = 0;
  for (int t = 0; t < 32; t++) {
    if (t + 1 < 32) STAGE(cur ^ 1, t + 1);
    short8 ah[4], al[4], bh[4], bl[4];
    #pragma unroll
    for (int f = 0; f < 4; f++) {
      int ra = (wr * 64 + f * 16 + cl) * 32 + g * 8;
      int rb = (wc * 64 + f * 16 + cl) * 32 + g * 8;
      ah[f] = *(const short8*)&sAh[cur][ra];
      al[f] = *(const short8*)&sAl[cur][ra];
      bh[f] = *(const short8*)&sBh[cur][rb];
      bl[f] = *(const short8*)&sBl[cur][rb];
    }
    #pragma unroll
    for (int fi = 0; fi < 4; fi++)
      #pragma unroll
      for (int fj = 0; fj < 4; fj++) {
        acc[fi][fj] = __builtin_amdgcn_mfma_f32_16x16x32_bf16(ah[fi], bh[fj], acc[fi][fj], 0, 0, 0);
        acc[fi][fj] = __builtin_amdgcn_mfma_f32_16x16x32_bf16(al[fi], bh[fj], acc[fi][fj], 0, 0, 0);
        acc[fi][fj] = __builtin_amdgcn_mfma_f32_16x16x32_bf16(ah[fi], bl[fj], acc[fi][fj], 0, 0, 0);
      }
    __syncthreads();
    cur ^= 1;
  }

  #pragma unroll
  for (int fi = 0; fi < 4; fi++)
    #pragma unroll
    for (int fj = 0; fj < 4; fj++)
      #pragma unroll
      for (int reg = 0; reg < 4; reg++) {
        int m = m0 + wr * 64 + fi * 16 + 4 * g + reg;
        int n = n0l + wc * 64 + fj * 16 + cl;
        out[(size_t)m * 1024 + n] = acc[fi][fj][reg] + bias[n];
      }
}

// ---------------------------------------------------------------------------
// attention helpers (unchanged from round 2)
// ---------------------------------------------------------------------------
__device__ __forceinline__ void stage8(ushort_t* region, const ushort_t* grow0,
                                       int r0, int lane, int rmax) {
  int flat16 = r0 * 8 + lane;
  int row = flat16 >> 3;
  int ch = flat16 & 7;
  int gr = row > rmax ? rmax : row;
  const ushort_t* src = grow0 + (size_t)gr * 64 + ((((ch << 4) ^ ((row & 7) << 4))) >> 1);
  gload16(src, region + r0 * 64);
}

__device__ __forceinline__ short8 ldsw(const ushort_t* base, int row, int offB) {
  const char* p = (const char*)base + row * 128 + (offB ^ ((row & 7) << 4));
  return *(const short8*)p;
}

// ---------------------------------------------------------------------------
// MFMA flash attention with exact Transformer-XL rel_shift (round-2 verified),
// epilogue now emits hi/lo bf16 split of att for the split merge GEMM.
// ---------------------------------------------------------------------------
__global__ void __launch_bounds__(256, 3) attn_mfma_kernel(
    const ushort_t* __restrict__ qu_g, const ushort_t* __restrict__ qv_g,
    const ushort_t* __restrict__ k_g, const ushort_t* __restrict__ v_g,
    const ushort_t* __restrict__ r_g,
    ushort_t* __restrict__ att_h, ushort_t* __restrict__ att_l)
{
    __shared__ ushort_t sQu[64 * 64];
    __shared__ ushort_t sQv[72 * 64];
    __shared__ ushort_t sK[64 * 64];
    __shared__ ushort_t sVt[64 * 72];
    __shared__ ushort_t sG[4 * 2176];

    const int tid = threadIdx.x;
    const int w = tid >> 6;
    const int lane = tid & 63;
    const int g = lane >> 4;
    const int cl = lane & 15;

    const int i0 = blockIdx.x * 64;
    const int h = blockIdx.y;
    const int b = blockIdx.z;
    const size_t base_bh = ((size_t)(b * HH + h)) * TT * DD;
    const ushort_t* rh = r_g + (size_t)h * TT * DD;

    ushort_t* Gw = sG + w * 2176;
    ushort_t* Pb = Gw;

    {
        const ushort_t* qub = qu_g + base_bh + (size_t)i0 * 64;
        stage8(sQu, qub, 16 * w, lane, 63);
        stage8(sQu, qub, 16 * w + 8, lane, 63);
        const ushort_t* qvb = qv_g + base_bh + (size_t)i0 * 64;
        int qvmax = 1023 - i0;
        stage8(sQv, qvb, 16 * w, lane, qvmax);
        stage8(sQv, qvb, 16 * w + 8, lane, qvmax);
        if (w == 0) stage8(sQv, qvb, 64, lane, qvmax);
    }
    __syncthreads();

    short8 aQ0 = ldsw(sQu, 16 * w + cl, 16 * g);
    short8 aQ1 = ldsw(sQu, 16 * w + cl, 64 + 16 * g);

    f32x4 Oa[4];
    #pragma unroll
    for (int q = 0; q < 4; q++) Oa[q] = (f32x4){0.f, 0.f, 0.f, 0.f};
    float mrun[4] = {-1e30f, -1e30f, -1e30f, -1e30f};
    float lrun[4] = {0.f, 0.f, 0.f, 0.f};

    for (int jt16 = 0; jt16 < 16; jt16++) {
        const int j0 = jt16 * 64;
        const int dji = j0 - i0;

        {
            const ushort_t* kb = k_g + base_bh + (size_t)j0 * 64;
            stage8(sK, kb, 16 * w, lane, 63);
            stage8(sK, kb, 16 * w + 8, lane, 63);
        }
        {
            int jj = tid & 63;
            int d0 = (tid >> 6) * 16;
            const ushort_t* vs = v_g + base_bh + (size_t)(j0 + jj) * 64 + d0;
            short8 v0 = *(const short8*)vs;
            short8 v1 = *(const short8*)(vs + 8);
            #pragma unroll
            for (int e = 0; e < 8; e++) sVt[(d0 + e) * 72 + jj] = (ushort_t)v0[e];
            #pragma unroll
            for (int e = 0; e < 8; e++) sVt[(d0 + 8 + e) * 72 + jj] = (ushort_t)v1[e];
        }
        __syncthreads();

        f32x4 sacc[4];
        #pragma unroll
        for (int jt = 0; jt < 4; jt++) sacc[jt] = (f32x4){0.f, 0.f, 0.f, 0.f};
        #pragma unroll
        for (int jt = 0; jt < 4; jt++) {
            int krow = jt * 16 + cl;
            short8 b0 = ldsw(sK, krow, 16 * g);
            short8 b1 = ldsw(sK, krow, 64 + 16 * g);
            sacc[jt] = __builtin_amdgcn_mfma_f32_16x16x32_bf16(aQ0, b0, sacc[jt], 0, 0, 0);
            sacc[jt] = __builtin_amdgcn_mfma_f32_16x16x32_bf16(aQ1, b1, sacc[jt], 0, 0, 0);
        }

        if (dji <= 0) {
            int cbase = 960 + dji;
            int nsub = (dji == 0) ? 4 : 8;
            int arow = 16 * w + cl;
            short8 aV0 = ldsw(sQv, arow, 16 * g);
            short8 aV1 = ldsw(sQv, arow, 64 + 16 * g);
            for (int sub = 0; sub < nsub; sub++) {
                int m = sub * 16 + cl;
                int rr = cbase + m;
                rr = rr < 0 ? 0 : (rr > 1023 ? 1023 : rr);
                const ushort_t* rp = rh + (size_t)rr * 64 + 8 * g;
                f32x4 gacc = (f32x4){0.f, 0.f, 0.f, 0.f};
                gacc = __builtin_amdgcn_mfma_f32_16x16x32_bf16(aV0, *(const short8*)rp, gacc, 0, 0, 0);
                gacc = __builtin_amdgcn_mfma_f32_16x16x32_bf16(aV1, *(const short8*)(rp + 32), gacc, 0, 0, 0);
                uint2 pk;
                pk.x = (uint_t)f2bf(gacc[0]) | ((uint_t)f2bf(gacc[1]) << 16);
                pk.y = (uint_t)f2bf(gacc[2]) | ((uint_t)f2bf(gacc[3]) << 16);
                *(uint2*)(Gw + m * 16 + 4 * g) = pk;
            }
            int lim = 63 - dji;
            #pragma unroll
            for (int jt = 0; jt < 4; jt++)
                #pragma unroll
                for (int reg = 0; reg < 4; reg++) {
                    int m1 = 63 + jt * 16 + cl - 16 * w - 4 * g - reg;
                    if (m1 <= lim) sacc[jt][reg] += bf2f(Gw[m1 * 16 + 4 * g + reg]);
                }
        }
        if (dji >= 0) {
            int cb2 = dji - 65; if (cb2 < 0) cb2 = 0;
            int nsub = (dji == 0) ? 4 : 8;
            int arow = 1 + 16 * w + cl;
            short8 aV0 = ldsw(sQv, arow, 16 * g);
            short8 aV1 = ldsw(sQv, arow, 64 + 16 * g);
            for (int sub = 0; sub < nsub; sub++) {
                int m = sub * 16 + cl;
                int rr = cb2 + m;
                rr = rr > 1023 ? 1023 : rr;
                const ushort_t* rp = rh + (size_t)rr * 64 + 8 * g;
                f32x4 gacc = (f32x4){0.f, 0.f, 0.f, 0.f};
                gacc = __builtin_amdgcn_mfma_f32_16x16x32_bf16(aV0, *(const short8*)rp, gacc, 0, 0, 0);
                gacc = __builtin_amdgcn_mfma_f32_16x16x32_bf16(aV1, *(const short8*)(rp + 32), gacc, 0, 0, 0);
                uint2 pk;
                pk.x = (uint_t)f2bf(gacc[0]) | ((uint_t)f2bf(gacc[1]) << 16);
                pk.y = (uint_t)f2bf(gacc[2]) | ((uint_t)f2bf(gacc[3]) << 16);
                *(uint2*)(Gw + m * 16 + 4 * g) = pk;
            }
            #pragma unroll
            for (int jt = 0; jt < 4; jt++)
                #pragma unroll
                for (int reg = 0; reg < 4; reg++) {
                    int dlt = dji + jt * 16 + cl - 16 * w - 4 * g - reg;
                    if (dlt >= 2) sacc[jt][reg] += bf2f(Gw[(dlt - 2 - cb2) * 16 + 4 * g + reg]);
                }
        }

        #pragma unroll
        for (int reg = 0; reg < 4; reg++) {
            float tmax = fmaxf(fmaxf(sacc[0][reg], sacc[1][reg]),
                               fmaxf(sacc[2][reg], sacc[3][reg]));
            #pragma unroll
            for (int msk = 1; msk <= 8; msk <<= 1) tmax = fmaxf(tmax, __shfl_xor(tmax, msk));
            float mnew = fmaxf(mrun[reg], tmax);
            float sc = __expf(mrun[reg] - mnew);
            mrun[reg] = mnew;
            float psum = 0.f;
            #pragma unroll
            for (int jt = 0; jt < 4; jt++) {
                float p = __expf(sacc[jt][reg] - mnew);
                psum += p;
                Pb[(4 * g + reg) * 72 + jt * 16 + cl] = f2bf(p);
            }
            #pragma unroll
            for (int msk = 1; msk <= 8; msk <<= 1) psum += __shfl_xor(psum, msk);
            lrun[reg] = lrun[reg] * sc + psum;
            #pragma unroll
            for (int q = 0; q < 4; q++) Oa[q][reg] *= sc;
        }

        #pragma unroll
        for (int kk = 0; kk < 2; kk++) {
            short8 aP = *(const short8*)((const char*)Pb + cl * 144 + 64 * kk + 16 * g);
            #pragma unroll
            for (int q = 0; q < 4; q++) {
                int vrow = q * 16 + cl;
                short8 bV = *(const short8*)((const char*)sVt + vrow * 144 + 64 * kk + 16 * g);
                Oa[q] = __builtin_amdgcn_mfma_f32_16x16x32_bf16(aP, bV, Oa[q], 0, 0, 0);
            }
        }
        __syncthreads();
    }

    float inv[4];
    #pragma unroll
    for (int reg = 0; reg < 4; reg++) inv[reg] = 1.f / lrun[reg];
    #pragma unroll
    for (int q = 0; q < 4; q++)
        #pragma unroll
        for (int reg = 0; reg < 4; reg++) {
            int i = i0 + 16 * w + 4 * g + reg;
            int d = q * 16 + cl;
            float val = Oa[q][reg] * inv[reg];
            ushort_t hi = f2bf(val);
            ushort_t lo = f2bf(val - bf2f(hi));
            size_t oi = (((size_t)(b * TT + i)) * HH + h) * DD + d;
            att_h[oi] = hi;
            att_l[oi] = lo;
        }
}

extern "C" void kernel_launch(void* const* d_in, const int* in_sizes, int n_in,
                              void* d_out, int out_size, void* d_ws, size_t ws_size,
                              hipStream_t stream) {
    const float* x    = (const float*)d_in[0];
    const float* pos  = (const float*)d_in[1];
    const float* Wq   = (const float*)d_in[2];
    const float* Wk   = (const float*)d_in[3];
    const float* Wv   = (const float*)d_in[4];
    const float* Wr   = (const float*)d_in[5];
    const float* ub   = (const float*)d_in[6];
    const float* vb   = (const float*)d_in[7];
    const float* mW   = (const float*)d_in[8];
    const float* mb   = (const float*)d_in[9];
    float* out = (float*)d_out;

    const size_t M1 = 1u << 20;  // 1M elements
    ushort_t* ws = (ushort_t*)d_ws;
    ushort_t* xb   = ws;                 // 4M
    ushort_t* posb = ws + 4 * M1;        // 1M
    ushort_t* wqt  = ws + 5 * M1;        // 1M
    ushort_t* wkt  = ws + 6 * M1;        // 1M
    ushort_t* wvt  = ws + 7 * M1;        // 1M
    ushort_t* wrt  = ws + 8 * M1;        // 1M
    ushort_t* wmh  = ws + 9 * M1;        // 1M
    ushort_t* wml  = ws + 10 * M1;       // 1M
    ushort_t* qu_g = ws + 11 * M1;       // 4M
    ushort_t* qv_g = ws + 15 * M1;       // 4M
    ushort_t* k_g  = ws + 19 * M1;       // 4M
    ushort_t* v_g  = ws + 23 * M1;       // 4M
    ushort_t* r_g  = ws + 27 * M1;       // 1M
    ushort_t* ath  = ws + 28 * M1;       // 4M
    ushort_t* atl  = ws + 32 * M1;       // 4M  -> total 36M elts = 72MB

    dim3 blk(256);

    // converts
    hipLaunchKernelGGL(conv_flat, dim3(2048), blk, 0, stream, x, xb, 4194304);
    hipLaunchKernelGGL(conv_flat, dim3(512), blk, 0, stream, pos, posb, 1048576);
    dim3 gtr(16, 16);
    hipLaunchKernelGGL(trans_conv, gtr, blk, 0, stream, Wq, wqt, (ushort_t*)nullptr, 0);
    hipLaunchKernelGGL(trans_conv, gtr, blk, 0, stream, Wk, wkt, (ushort_t*)nullptr, 0);
    hipLaunchKernelGGL(trans_conv, gtr, blk, 0, stream, Wv, wvt, (ushort_t*)nullptr, 0);
    hipLaunchKernelGGL(trans_conv, gtr, blk, 0, stream, Wr, wrt, (ushort_t*)nullptr, 0);
    hipLaunchKernelGGL(trans_conv, gtr, blk, 0, stream, mW, wmh, wml, 1);

    // fused q/k/v projections (N = 3 x 1024), grid 24 x 32
    hipLaunchKernelGGL(mfma_gemm_proj, dim3(24, 32), blk, 0, stream,
                       xb, wqt, wkt, wvt, qu_g, qv_g, k_g, v_g, ub, vb, 0);
    // r projection, grid 8 x 8
    hipLaunchKernelGGL(mfma_gemm_proj, dim3(8, 8), blk, 0, stream,
                       posb, wrt, wrt, wrt, r_g, r_g, r_g, r_g, ub, vb, 1);

    // attention
    hipLaunchKernelGGL(attn_mfma_kernel, dim3(TT / 64, HH, BB), blk, 0, stream,
                       qu_g, qv_g, k_g, v_g, r_g, ath, atl);

    // split merge GEMM, grid 8 x 32
    hipLaunchKernelGGL(mfma_gemm_merge, dim3(8, 32), blk, 0, stream,
                       ath, atl, wmh, wml, mb, out);
}

// Round 6
// 333.266 us; speedup vs baseline: 8.7631x; 1.1460x over previous
//
#include <hip/hip_runtime.h>
#include <hip/hip_bf16.h>

#define BB 4
#define TT 1024
#define EE 1024
#define HH 16
#define DD 64

typedef unsigned short ushort_t;
typedef unsigned int uint_t;
typedef __attribute__((ext_vector_type(8))) short short8;
typedef __attribute__((ext_vector_type(4))) float f32x4;

__device__ __forceinline__ ushort_t f2bf(float f) {
  uint_t u = __float_as_uint(f);
  u += 0x7fffu + ((u >> 16) & 1u);
  return (ushort_t)(u >> 16);
}
__device__ __forceinline__ float bf2f(ushort_t s) {
  return __uint_as_float(((uint_t)s) << 16);
}

// async global->LDS, 16B per lane; dst is wave-uniform base (HW adds lane*16)
__device__ __forceinline__ void gload16(const ushort_t* src, ushort_t* dst) {
  __builtin_amdgcn_global_load_lds(
      (const __attribute__((address_space(1))) void*)src,
      (__attribute__((address_space(3))) void*)dst, 16, 0, 0);
}

// ---------------------------------------------------------------------------
// flat fp32 -> bf16 convert (n multiple of 2048)
// ---------------------------------------------------------------------------
__global__ void __launch_bounds__(256) conv_flat(
    const float* __restrict__ in, ushort_t* __restrict__ out, int n) {
  int i = (blockIdx.x * 256 + threadIdx.x) * 8;
  if (i >= n) return;
  float4 a = *(const float4*)(in + i);
  float4 b = *(const float4*)(in + i + 4);
  uint4 o;
  o.x = (uint_t)f2bf(a.x) | ((uint_t)f2bf(a.y) << 16);
  o.y = (uint_t)f2bf(a.z) | ((uint_t)f2bf(a.w) << 16);
  o.z = (uint_t)f2bf(b.x) | ((uint_t)f2bf(b.y) << 16);
  o.w = (uint_t)f2bf(b.z) | ((uint_t)f2bf(b.w) << 16);
  *(uint4*)(out + i) = o;
}

// ---------------------------------------------------------------------------
// transpose + convert: Oh[n][k] = bf16(W[k][n]); optional lo residual
// ---------------------------------------------------------------------------
__global__ void __launch_bounds__(256) trans_conv(
    const float* __restrict__ W, ushort_t* __restrict__ Oh,
    ushort_t* __restrict__ Ol, int has_lo) {
  __shared__ float Ts[64][65];
  const int n0 = blockIdx.x * 64, k0 = blockIdx.y * 64;
  const int t = threadIdx.x;
  const int r = t >> 2, cs = (t & 3) * 16;
  const float* src = W + (size_t)(k0 + r) * 1024 + n0 + cs;
  #pragma unroll
  for (int e = 0; e < 16; e += 4) {
    float4 v4 = *(const float4*)(src + e);
    Ts[r][cs + e] = v4.x; Ts[r][cs + e + 1] = v4.y;
    Ts[r][cs + e + 2] = v4.z; Ts[r][cs + e + 3] = v4.w;
  }
  __syncthreads();
  ushort_t hb[16], lb[16];
  #pragma unroll
  for (int e = 0; e < 16; e++) {
    float v = Ts[cs + e][r];
    hb[e] = f2bf(v);
    lb[e] = f2bf(v - bf2f(hb[e]));
  }
  ushort_t* dh = Oh + (size_t)(n0 + r) * 1024 + k0 + cs;
  *(uint4*)dh = *(const uint4*)hb;
  *(uint4*)(dh + 8) = *(const uint4*)(hb + 8);
  if (has_lo) {
    ushort_t* dl = Ol + (size_t)(n0 + r) * 1024 + k0 + cs;
    *(uint4*)dl = *(const uint4*)lb;
    *(uint4*)(dl + 8) = *(const uint4*)(lb + 8);
  }
}

// ---------------------------------------------------------------------------
// MFMA GEMM (m97 structure), modes as round 3
// ---------------------------------------------------------------------------
__global__ void __launch_bounds__(256) mfma_gemm_proj(
    const ushort_t* __restrict__ A,
    const ushort_t* __restrict__ B0, const ushort_t* __restrict__ B1,
    const ushort_t* __restrict__ B2,
    ushort_t* __restrict__ o_qu, ushort_t* __restrict__ o_qv,
    ushort_t* __restrict__ o_k, ushort_t* __restrict__ o_v,
    const float* __restrict__ bias_u, const float* __restrict__ bias_v,
    int mode) {
  __shared__ ushort_t sA[2][128 * 32];
  __shared__ ushort_t sB[2][128 * 32];
  const int tid = threadIdx.x;
  const int w = tid >> 6, lane = tid & 63, g = lane >> 4, cl = lane & 15;
  const int wr = w >> 1, wc = w & 1;

  int widx, n0l;
  const ushort_t* Bt;
  if (mode == 0) {
    widx = blockIdx.x >> 3;
    n0l = (blockIdx.x & 7) * 128;
    Bt = (widx == 0) ? B0 : ((widx == 1) ? B1 : B2);
  } else {
    widx = 3;
    n0l = blockIdx.x * 128;
    Bt = B0;
  }
  const int m0 = blockIdx.y * 128;

  f32x4 acc[4][4];
  #pragma unroll
  for (int fi = 0; fi < 4; fi++)
    #pragma unroll
    for (int fj = 0; fj < 4; fj++) acc[fi][fj] = (f32x4){0.f, 0.f, 0.f, 0.f};

  auto STAGE = [&](int buf, int t) {
    const int k0b = t * 64;
    #pragma unroll
    for (int i = 0; i < 2; i++) {
      int cb = w * 128 + i * 64;
      int c = cb + lane;
      const char* sa = (const char*)A + (size_t)(m0 + (c >> 2)) * 2048 + k0b + (c & 3) * 16;
      gload16((const ushort_t*)sa, &sA[buf][cb * 8]);
      const char* sb = (const char*)Bt + (size_t)(n0l + (c >> 2)) * 2048 + k0b + (c & 3) * 16;
      gload16((const ushort_t*)sb, &sB[buf][cb * 8]);
    }
  };

  STAGE(0, 0);
  __syncthreads();
  int cur = 0;
  for (int t = 0; t < 32; t++) {
    if (t + 1 < 32) STAGE(cur ^ 1, t + 1);
    short8 af[4], bfr[4];
    #pragma unroll
    for (int f = 0; f < 4; f++) {
      af[f] = *(const short8*)&sA[cur][(wr * 64 + f * 16 + cl) * 32 + g * 8];
      bfr[f] = *(const short8*)&sB[cur][(wc * 64 + f * 16 + cl) * 32 + g * 8];
    }
    #pragma unroll
    for (int fi = 0; fi < 4; fi++)
      #pragma unroll
      for (int fj = 0; fj < 4; fj++)
        acc[fi][fj] = __builtin_amdgcn_mfma_f32_16x16x32_bf16(af[fi], bfr[fj], acc[fi][fj], 0, 0, 0);
    __syncthreads();
    cur ^= 1;
  }

  #pragma unroll
  for (int fi = 0; fi < 4; fi++)
    #pragma unroll
    for (int fj = 0; fj < 4; fj++)
      #pragma unroll
      for (int reg = 0; reg < 4; reg++) {
        int m = m0 + wr * 64 + fi * 16 + 4 * g + reg;
        int n = n0l + wc * 64 + fj * 16 + cl;
        float val = acc[fi][fj][reg];
        int h = n >> 6, d = n & 63;
        if (mode == 0) {
          int b = m >> 10, tt = m & 1023;
          size_t idx = (((size_t)(b * HH + h)) * TT + tt) * DD + d;
          if (widx == 0) {
            float s = val * 0.125f;
            o_qu[idx] = f2bf(s + bias_u[n]);
            o_qv[idx] = f2bf(s + bias_v[n]);
          } else if (widx == 1) {
            o_k[idx] = f2bf(val);
          } else {
            o_v[idx] = f2bf(val);
          }
        } else {
          size_t idx = ((size_t)h * TT + m) * DD + d;
          o_qu[idx] = f2bf(val);
        }
      }
}

// ---------------------------------------------------------------------------
// Split-bf16 merge GEMM: out = (Ah+Al) @ (Wh+Wl)^T + b  (drop Al@Wl term)
// ---------------------------------------------------------------------------
__global__ void __launch_bounds__(256) mfma_gemm_merge(
    const ushort_t* __restrict__ Ah, const ushort_t* __restrict__ Al,
    const ushort_t* __restrict__ Bh, const ushort_t* __restrict__ Bl,
    const float* __restrict__ bias, float* __restrict__ out) {
  __shared__ ushort_t sAh[2][128 * 32], sAl[2][128 * 32];
  __shared__ ushort_t sBh[2][128 * 32], sBl[2][128 * 32];
  const int tid = threadIdx.x;
  const int w = tid >> 6, lane = tid & 63, g = lane >> 4, cl = lane & 15;
  const int wr = w >> 1, wc = w & 1;
  const int n0l = blockIdx.x * 128;
  const int m0 = blockIdx.y * 128;

  f32x4 acc[4][4];
  #pragma unroll
  for (int fi = 0; fi < 4; fi++)
    #pragma unroll
    for (int fj = 0; fj < 4; fj++) acc[fi][fj] = (f32x4){0.f, 0.f, 0.f, 0.f};

  auto STAGE = [&](int buf, int t) {
    const int k0b = t * 64;
    #pragma unroll
    for (int i = 0; i < 2; i++) {
      int cb = w * 128 + i * 64;
      int c = cb + lane;
      size_t offA = (size_t)(m0 + (c >> 2)) * 2048 + k0b + (c & 3) * 16;
      size_t offB = (size_t)(n0l + (c >> 2)) * 2048 + k0b + (c & 3) * 16;
      gload16((const ushort_t*)((const char*)Ah + offA), &sAh[buf][cb * 8]);
      gload16((const ushort_t*)((const char*)Al + offA), &sAl[buf][cb * 8]);
      gload16((const ushort_t*)((const char*)Bh + offB), &sBh[buf][cb * 8]);
      gload16((const ushort_t*)((const char*)Bl + offB), &sBl[buf][cb * 8]);
    }
  };

  STAGE(0, 0);
  __syncthreads();
  int cur = 0;
  for (int t = 0; t < 32; t++) {
    if (t + 1 < 32) STAGE(cur ^ 1, t + 1);
    short8 ah[4], al[4], bh[4], bl[4];
    #pragma unroll
    for (int f = 0; f < 4; f++) {
      int ra = (wr * 64 + f * 16 + cl) * 32 + g * 8;
      int rb = (wc * 64 + f * 16 + cl) * 32 + g * 8;
      ah[f] = *(const short8*)&sAh[cur][ra];
      al[f] = *(const short8*)&sAl[cur][ra];
      bh[f] = *(const short8*)&sBh[cur][rb];
      bl[f] = *(const short8*)&sBl[cur][rb];
    }
    #pragma unroll
    for (int fi = 0; fi < 4; fi++)
      #pragma unroll
      for (int fj = 0; fj < 4; fj++) {
        acc[fi][fj] = __builtin_amdgcn_mfma_f32_16x16x32_bf16(ah[fi], bh[fj], acc[fi][fj], 0, 0, 0);
        acc[fi][fj] = __builtin_amdgcn_mfma_f32_16x16x32_bf16(al[fi], bh[fj], acc[fi][fj], 0, 0, 0);
        acc[fi][fj] = __builtin_amdgcn_mfma_f32_16x16x32_bf16(ah[fi], bl[fj], acc[fi][fj], 0, 0, 0);
      }
    __syncthreads();
    cur ^= 1;
  }

  #pragma unroll
  for (int fi = 0; fi < 4; fi++)
    #pragma unroll
    for (int fj = 0; fj < 4; fj++)
      #pragma unroll
      for (int reg = 0; reg < 4; reg++) {
        int m = m0 + wr * 64 + fi * 16 + 4 * g + reg;
        int n = n0l + wc * 64 + fj * 16 + cl;
        out[(size_t)m * 1024 + n] = acc[fi][fj][reg] + bias[n];
      }
}

// ---------------------------------------------------------------------------
// K staging: 8 rows (1KB) of [rows][64 bf16], XOR-swizzle pre-applied on the
// GLOBAL source (LDS linear). read: byte' = byte ^ ((row&7)<<4)
// ---------------------------------------------------------------------------
__device__ __forceinline__ void stage8(ushort_t* region, const ushort_t* grow0,
                                       int r0, int lane, int rmax) {
  int flat16 = r0 * 8 + lane;
  int row = flat16 >> 3;
  int ch = flat16 & 7;
  int gr = row > rmax ? rmax : row;
  const ushort_t* src = grow0 + (size_t)gr * 64 + ((((ch << 4) ^ ((row & 7) << 4))) >> 1);
  gload16(src, region + r0 * 64);
}

__device__ __forceinline__ short8 ldsw(const ushort_t* base, int row, int offB) {
  const char* p = (const char*)base + row * 128 + (offB ^ ((row & 7) << 4));
  return *(const short8*)p;
}

// ---------------------------------------------------------------------------
// MFMA flash attention, exact Transformer-XL rel_shift (round-2/3-verified
// math, byte-identical index formulas). Structure: double-buffered K
// (global_load_lds) + double-buffered V^T with async-split staging
// (global->reg issued mid-tile, reg->LDS transpose write after PV),
// Q fragments in registers, stride-18 G buffer, diagonal-tile disjoint G2.
// PV uses the round-3 PROVEN sVt[d][j] layout + plain ds_read_b128
// (the round-4/5 ds_read_b64_tr_b16 path was the unverifiable suspect).
// rel_shift(i,j): j<=i -> qv[i].r[T-1+j-i]; j==i+1 -> 0; j>=i+2 -> qv[i+1].r[j-i-2]
// ---------------------------------------------------------------------------
__global__ void __launch_bounds__(256, 3) attn_mfma_kernel(
    const ushort_t* __restrict__ qu_g, const ushort_t* __restrict__ qv_g,
    const ushort_t* __restrict__ k_g, const ushort_t* __restrict__ v_g,
    const ushort_t* __restrict__ r_g,
    ushort_t* __restrict__ att_h, ushort_t* __restrict__ att_l)
{
    __shared__ ushort_t sK[2][64 * 64];    // swizzled rows (stage8/ldsw), 16 KB
    __shared__ ushort_t sVt[2][64 * 72];   // V^T [d][j], 144B rows, 18 KB
    __shared__ ushort_t sG[4][2304];       // per-wave G (stride 18) / P (stride 72)

    const int tid = threadIdx.x;
    const int w = tid >> 6;
    const int lane = tid & 63;
    const int g = lane >> 4;
    const int cl = lane & 15;

    const int i0 = blockIdx.x * 64;
    const int h = blockIdx.y;
    const int b = blockIdx.z;
    const size_t base_bh = ((size_t)(b * HH + h)) * TT * DD;
    const ushort_t* rh = r_g + (size_t)h * TT * DD;

    ushort_t* Gw = sG[w];
    ushort_t* Pb = sG[w];

    // ---- Q fragments in registers (one-time global/L2 reads) ----
    const int qrow = i0 + 16 * w + cl;
    const ushort_t* qup = qu_g + base_bh + (size_t)qrow * 64;
    short8 aQ0 = *(const short8*)(qup + 8 * g);
    short8 aQ1 = *(const short8*)(qup + 32 + 8 * g);
    const ushort_t* qv1p = qv_g + base_bh + (size_t)qrow * 64;
    short8 aV0 = *(const short8*)(qv1p + 8 * g);
    short8 aV1 = *(const short8*)(qv1p + 32 + 8 * g);
    int r2row = qrow + 1; if (r2row > 1023) r2row = 1023;  // clamped row never gathered
    const ushort_t* qv2p = qv_g + base_bh + (size_t)r2row * 64;
    short8 aV0s = *(const short8*)(qv2p + 8 * g);
    short8 aV1s = *(const short8*)(qv2p + 32 + 8 * g);

    // ---- staging helpers ----
    auto STAGEK = [&](int bufi, int jt16) {
      const ushort_t* kb = k_g + base_bh + (size_t)(jt16 * 64) * 64;
      stage8(sK[bufi], kb, 16 * w, lane, 63);
      stage8(sK[bufi], kb, 16 * w + 8, lane, 63);
    };
    const int vjj = tid & 63;
    const int vd0 = (tid >> 6) * 16;
    auto LOADV = [&](int jt16, short8& v0, short8& v1) {
      const ushort_t* vs = v_g + base_bh + (size_t)(jt16 * 64 + vjj) * 64 + vd0;
      v0 = *(const short8*)vs;
      v1 = *(const short8*)(vs + 8);
    };
    auto WRITEV = [&](int bufi, short8 v0, short8 v1) {
      ushort_t* dst = &sVt[bufi][0];
      #pragma unroll
      for (int e = 0; e < 8; e++) dst[(vd0 + e) * 72 + vjj] = (ushort_t)v0[e];
      #pragma unroll
      for (int e = 0; e < 8; e++) dst[(vd0 + 8 + e) * 72 + vjj] = (ushort_t)v1[e];
    };

    f32x4 Oa[4];
    #pragma unroll
    for (int q = 0; q < 4; q++) Oa[q] = (f32x4){0.f, 0.f, 0.f, 0.f};
    float mrun[4] = {-1e30f, -1e30f, -1e30f, -1e30f};
    float lrun[4] = {0.f, 0.f, 0.f, 0.f};

    // ---- prologue: tile 0 ----
    STAGEK(0, 0);
    short8 pv0, pv1;
    LOADV(0, pv0, pv1);
    WRITEV(0, pv0, pv1);
    __syncthreads();
    int cur = 0;

    for (int jt16 = 0; jt16 < 16; jt16++) {
        const int j0 = jt16 * 64;
        const int dji = j0 - i0;
        // diagonal tiles run BOTH branches: branch2 gets a disjoint G region
        ushort_t* Gw2 = Gw + ((dji == 0) ? 64 * 18 : 0);

        // ---- content scores: S = Qu @ K^T ----
        f32x4 sacc[4];
        #pragma unroll
        for (int jt = 0; jt < 4; jt++) sacc[jt] = (f32x4){0.f, 0.f, 0.f, 0.f};
        __builtin_amdgcn_s_setprio(1);
        #pragma unroll
        for (int jt = 0; jt < 4; jt++) {
            int krow = jt * 16 + cl;
            short8 b0 = ldsw(sK[cur], krow, 16 * g);
            short8 b1 = ldsw(sK[cur], krow, 64 + 16 * g);
            sacc[jt] = __builtin_amdgcn_mfma_f32_16x16x32_bf16(aQ0, b0, sacc[jt], 0, 0, 0);
            sacc[jt] = __builtin_amdgcn_mfma_f32_16x16x32_bf16(aQ1, b1, sacc[jt], 0, 0, 0);
        }
        __builtin_amdgcn_s_setprio(0);

        // ---- windowed G GEMM (rel term), r read from global/L2 ----
        if (dji <= 0) {
            int cbase = 960 + dji;
            int nsub = (dji == 0) ? 4 : 8;
            for (int sub = 0; sub < nsub; sub++) {
                int m = sub * 16 + cl;
                int rr = cbase + m;
                rr = rr < 0 ? 0 : (rr > 1023 ? 1023 : rr);
                const ushort_t* rp = rh + (size_t)rr * 64 + 8 * g;
                f32x4 gacc = (f32x4){0.f, 0.f, 0.f, 0.f};
                gacc = __builtin_amdgcn_mfma_f32_16x16x32_bf16(aV0, *(const short8*)rp, gacc, 0, 0, 0);
                gacc = __builtin_amdgcn_mfma_f32_16x16x32_bf16(aV1, *(const short8*)(rp + 32), gacc, 0, 0, 0);
                *(uint_t*)(Gw + m * 18 + 4 * g) =
                    (uint_t)f2bf(gacc[0]) | ((uint_t)f2bf(gacc[1]) << 16);
                *(uint_t*)(Gw + m * 18 + 4 * g + 2) =
                    (uint_t)f2bf(gacc[2]) | ((uint_t)f2bf(gacc[3]) << 16);
            }
        }
        if (dji >= 0) {
            int cb2 = dji - 65; if (cb2 < 0) cb2 = 0;
            int nsub = (dji == 0) ? 4 : 8;
            for (int sub = 0; sub < nsub; sub++) {
                int m = sub * 16 + cl;
                int rr = cb2 + m;
                rr = rr > 1023 ? 1023 : rr;
                const ushort_t* rp = rh + (size_t)rr * 64 + 8 * g;
                f32x4 gacc = (f32x4){0.f, 0.f, 0.f, 0.f};
                gacc = __builtin_amdgcn_mfma_f32_16x16x32_bf16(aV0s, *(const short8*)rp, gacc, 0, 0, 0);
                gacc = __builtin_amdgcn_mfma_f32_16x16x32_bf16(aV1s, *(const short8*)(rp + 32), gacc, 0, 0, 0);
                *(uint_t*)(Gw2 + m * 18 + 4 * g) =
                    (uint_t)f2bf(gacc[0]) | ((uint_t)f2bf(gacc[1]) << 16);
                *(uint_t*)(Gw2 + m * 18 + 4 * g + 2) =
                    (uint_t)f2bf(gacc[2]) | ((uint_t)f2bf(gacc[3]) << 16);
            }
        }

        // ---- prefetch next K tile (async LDS) + next V tile (to regs) ----
        if (jt16 + 1 < 16) {
            STAGEK(cur ^ 1, jt16 + 1);
            LOADV(jt16 + 1, pv0, pv1);
        }

        // ---- gather shifted rel values into score fragments ----
        if (dji <= 0) {
            int lim = 63 - dji;
            #pragma unroll
            for (int jt = 0; jt < 4; jt++)
                #pragma unroll
                for (int reg = 0; reg < 4; reg++) {
                    int m1 = 63 + jt * 16 + cl - 16 * w - 4 * g - reg;
                    if (m1 <= lim) sacc[jt][reg] += bf2f(Gw[m1 * 18 + 4 * g + reg]);
                }
        }
        if (dji >= 0) {
            int cb2 = dji - 65; if (cb2 < 0) cb2 = 0;
            #pragma unroll
            for (int jt = 0; jt < 4; jt++)
                #pragma unroll
                for (int reg = 0; reg < 4; reg++) {
                    int dlt = dji + jt * 16 + cl - 16 * w - 4 * g - reg;
                    if (dlt >= 2) sacc[jt][reg] += bf2f(Gw2[(dlt - 2 - cb2) * 18 + 4 * g + reg]);
                }
        }

        // ---- online softmax ----
        #pragma unroll
        for (int reg = 0; reg < 4; reg++) {
            float tmax = fmaxf(fmaxf(sacc[0][reg], sacc[1][reg]),
                               fmaxf(sacc[2][reg], sacc[3][reg]));
            #pragma unroll
            for (int msk = 1; msk <= 8; msk <<= 1) tmax = fmaxf(tmax, __shfl_xor(tmax, msk));
            float mnew = fmaxf(mrun[reg], tmax);
            float sc = __expf(mrun[reg] - mnew);
            mrun[reg] = mnew;
            float psum = 0.f;
            #pragma unroll
            for (int jt = 0; jt < 4; jt++) {
                float p = __expf(sacc[jt][reg] - mnew);
                psum += p;
                Pb[(4 * g + reg) * 72 + jt * 16 + cl] = f2bf(p);
            }
            #pragma unroll
            for (int msk = 1; msk <= 8; msk <<= 1) psum += __shfl_xor(psum, msk);
            lrun[reg] = lrun[reg] * sc + psum;
            #pragma unroll
            for (int q = 0; q < 4; q++) Oa[q][reg] *= sc;
        }

        // ---- PV: O += P @ V  (proven round-3 sVt layout) ----
        __builtin_amdgcn_s_setprio(1);
        #pragma unroll
        for (int kk = 0; kk < 2; kk++) {
            short8 aP = *(const short8*)((const char*)Pb + cl * 144 + 64 * kk + 16 * g);
            #pragma unroll
            for (int q = 0; q < 4; q++) {
                int vrow = q * 16 + cl;
                short8 bV = *(const short8*)((const char*)&sVt[cur][0] + vrow * 144 + 64 * kk + 16 * g);
                Oa[q] = __builtin_amdgcn_mfma_f32_16x16x32_bf16(aP, bV, Oa[q], 0, 0, 0);
            }
        }
        __builtin_amdgcn_s_setprio(0);

        // ---- write prefetched V regs into the other buffer (transpose) ----
        if (jt16 + 1 < 16) WRITEV(cur ^ 1, pv0, pv1);

        __syncthreads();
        cur ^= 1;
    }

    // ---- epilogue: normalize, hi/lo bf16 split, store [B,T,H,D] ----
    float inv[4];
    #pragma unroll
    for (int reg = 0; reg < 4; reg++) inv[reg] = 1.f / lrun[reg];
    #pragma unroll
    for (int q = 0; q < 4; q++)
        #pragma unroll
        for (int reg = 0; reg < 4; reg++) {
            int i = i0 + 16 * w + 4 * g + reg;
            int d = q * 16 + cl;
            float val = Oa[q][reg] * inv[reg];
            ushort_t hi = f2bf(val);
            ushort_t lo = f2bf(val - bf2f(hi));
            size_t oi = (((size_t)(b * TT + i)) * HH + h) * DD + d;
            att_h[oi] = hi;
            att_l[oi] = lo;
        }
}

extern "C" void kernel_launch(void* const* d_in, const int* in_sizes, int n_in,
                              void* d_out, int out_size, void* d_ws, size_t ws_size,
                              hipStream_t stream) {
    const float* x    = (const float*)d_in[0];
    const float* pos  = (const float*)d_in[1];
    const float* Wq   = (const float*)d_in[2];
    const float* Wk   = (const float*)d_in[3];
    const float* Wv   = (const float*)d_in[4];
    const float* Wr   = (const float*)d_in[5];
    const float* ub   = (const float*)d_in[6];
    const float* vb   = (const float*)d_in[7];
    const float* mW   = (const float*)d_in[8];
    const float* mb   = (const float*)d_in[9];
    float* out = (float*)d_out;

    const size_t M1 = 1u << 20;
    ushort_t* ws = (ushort_t*)d_ws;
    ushort_t* xb   = ws;
    ushort_t* posb = ws + 4 * M1;
    ushort_t* wqt  = ws + 5 * M1;
    ushort_t* wkt  = ws + 6 * M1;
    ushort_t* wvt  = ws + 7 * M1;
    ushort_t* wrt  = ws + 8 * M1;
    ushort_t* wmh  = ws + 9 * M1;
    ushort_t* wml  = ws + 10 * M1;
    ushort_t* qu_g = ws + 11 * M1;
    ushort_t* qv_g = ws + 15 * M1;
    ushort_t* k_g  = ws + 19 * M1;
    ushort_t* v_g  = ws + 23 * M1;
    ushort_t* r_g  = ws + 27 * M1;
    ushort_t* ath  = ws + 28 * M1;
    ushort_t* atl  = ws + 32 * M1;

    dim3 blk(256);

    hipLaunchKernelGGL(conv_flat, dim3(2048), blk, 0, stream, x, xb, 4194304);
    hipLaunchKernelGGL(conv_flat, dim3(512), blk, 0, stream, pos, posb, 1048576);
    dim3 gtr(16, 16);
    hipLaunchKernelGGL(trans_conv, gtr, blk, 0, stream, Wq, wqt, (ushort_t*)nullptr, 0);
    hipLaunchKernelGGL(trans_conv, gtr, blk, 0, stream, Wk, wkt, (ushort_t*)nullptr, 0);
    hipLaunchKernelGGL(trans_conv, gtr, blk, 0, stream, Wv, wvt, (ushort_t*)nullptr, 0);
    hipLaunchKernelGGL(trans_conv, gtr, blk, 0, stream, Wr, wrt, (ushort_t*)nullptr, 0);
    hipLaunchKernelGGL(trans_conv, gtr, blk, 0, stream, mW, wmh, wml, 1);

    hipLaunchKernelGGL(mfma_gemm_proj, dim3(24, 32), blk, 0, stream,
                       xb, wqt, wkt, wvt, qu_g, qv_g, k_g, v_g, ub, vb, 0);
    hipLaunchKernelGGL(mfma_gemm_proj, dim3(8, 8), blk, 0, stream,
                       posb, wrt, wrt, wrt, r_g, r_g, r_g, r_g, ub, vb, 1);

    hipLaunchKernelGGL(attn_mfma_kernel, dim3(TT / 64, HH, BB), blk, 0, stream,
                       qu_g, qv_g, k_g, v_g, r_g, ath, atl);

    hipLaunchKernelGGL(mfma_gemm_merge, dim3(8, 32), blk, 0, stream,
                       ath, atl, wmh, wml, mb, out);
}